// Round 5
// baseline (629.960 us; speedup 1.0000x reference)
//
#include <hip/hip_runtime.h>
#include <math.h>

#define NT 65536
#define EE 1048576
#define NB 128
#define KK 410          // kept nodes per graph = ceil(0.8*512)
#define HH 128

typedef short bf16x8 __attribute__((ext_vector_type(8)));
typedef float f32x4 __attribute__((ext_vector_type(4)));

// ---------------- device scratch -------------------------------------------
// Slice-major layouts ([slice][node][F]): the fused conv gathers slice s for
// all its rows before moving to slice s+1; since all blocks advance through
// slices roughly together, each XCD's L2 holds the live slice (2MB) -> gathers
// are L2 hits (R10 measured: FETCH 162->19MB). No dispatch-mapping assumption.
__device__ __align__(16) unsigned short g_xbs[(size_t)8 * NT * 8];   // x bf16 [8][NT][8]
__device__ __align__(16) unsigned short g_hs1[(size_t)8 * NT * 16];  // h1 (then h3) bf16 [8][NT][16]
__device__ __align__(16) unsigned short g_hgs[(size_t)8 * NT * 16];  // gated h2 bf16 [8][NT][16]
__device__ __align__(16) unsigned short g_hb2[(size_t)NT * HH];      // h2 row-major (gateS input)
__device__ __align__(16) unsigned short g_wt1[128 * 128];
__device__ __align__(16) unsigned short g_wtc[3 * 128 * 256];
__device__ __align__(16) unsigned short g_csr1u[EE];   // src id per edge, grouped by dst
__device__ unsigned short g_keptu[NT];   // 1 if node kept by SAGPool
__device__ unsigned int g_ebuck[EE];     // packed (dstLocal<<16)|src, bucketed by graph
__device__ int g_bcnt[128];
__device__ int g_bbase[129];
__device__ int g_bcur[128];
__device__ float g_trel[NT];
__device__ float g_troot[NT];
__device__ float g_gatef[NT];            // tanh(score) if kept else 0
__device__ float g_kinv[NT];             // 1/max(kept-neighbor count,1)
__device__ float g_xc4[4 * NB * 4 * 128]; // pooled partials [sec][graph][quarter][128]
__device__ int g_rows1[NT + 1];

__device__ __forceinline__ float b2f(unsigned short u) {
    union { unsigned int i; float f; } v;
    v.i = ((unsigned int)u) << 16;
    return v.f;
}
__device__ __forceinline__ unsigned short f2b(float f) {
    unsigned int x = __float_as_uint(f);
    unsigned int r = x + 0x7fffu + ((x >> 16) & 1u);   // round-to-nearest-even
    return (unsigned short)(r >> 16);
}
__device__ __forceinline__ unsigned int pk2(float a, float b) {
    return (unsigned int)f2b(a) | ((unsigned int)f2b(b) << 16);
}
__device__ __forceinline__ unsigned int mul2(unsigned int wd, float g) {
    float lo = b2f((unsigned short)(wd & 0xffffu)) * g;
    float hi = b2f((unsigned short)(wd >> 16)) * g;
    return pk2(lo, hi);
}
__device__ __forceinline__ void acc2(float* a, unsigned int wd) {
    a[0] += b2f((unsigned short)(wd & 0xffffu));
    a[1] += b2f((unsigned short)(wd >> 16));
}

// ---------------- prep: x->bf16 slice-major, weights, zero bcnt -------------
// NOTE (R7): no grid-wide fences on CDNA4 (per-XCD L2) — kernel boundaries sync.
__global__ void k_prep(const float* __restrict__ x,
                       const float* __restrict__ W1r, const float* __restrict__ W1o,
                       const float* __restrict__ Wcr, const float* __restrict__ Wco) {
    int tid = blockIdx.x * 256 + threadIdx.x;
    if (tid < 1048576) {
        float4 v = *(const float4*)&x[(size_t)tid * 4];
        unsigned int lo = pk2(v.x, v.y);
        unsigned int hi = pk2(v.z, v.w);
        int node = tid >> 4;
        int sl = (tid & 15) >> 1;
        int of = (tid & 1) * 4;
        *(uint2*)&g_xbs[(((size_t)sl) * NT + node) * 8 + of] = make_uint2(lo, hi);
    } else if (tid < 1048576 + 16384) {
        int r = tid - 1048576;
        int k = r & 127, n = r >> 7;
        float v = (k < 64) ? W1r[k * 128 + n] : W1o[(k - 64) * 128 + n];
        g_wt1[n * 128 + k] = f2b(v);
    } else if (tid < 1048576 + 16384 + 98304) {
        int r = tid - (1048576 + 16384);
        int l = r >> 15;
        int k = r & 255, n = (r >> 8) & 127;
        float v = (k < 128) ? Wcr[l * 16384 + k * 128 + n]
                            : Wco[l * 16384 + (k - 128) * 128 + n];
        g_wtc[l * 32768 + n * 256 + k] = f2b(v);
    } else if (tid < 1048576 + 16384 + 98304 + 128) {
        g_bcnt[tid - (1048576 + 16384 + 98304)] = 0;
    }
}

// ---------------- CSR1 build: 2-level counting sort -------------------------
__global__ __launch_bounds__(256) void k_bhist(const int* __restrict__ dst) {
    __shared__ int h[128];
    if (threadIdx.x < 128) h[threadIdx.x] = 0;
    __syncthreads();
    int e0 = (blockIdx.x * 256 + threadIdx.x) * 4;
    int4 d = *(const int4*)&dst[e0];
    atomicAdd(&h[d.x >> 9], 1);
    atomicAdd(&h[d.y >> 9], 1);
    atomicAdd(&h[d.z >> 9], 1);
    atomicAdd(&h[d.w >> 9], 1);
    __syncthreads();
    if (threadIdx.x < 128 && h[threadIdx.x]) atomicAdd(&g_bcnt[threadIdx.x], h[threadIdx.x]);
}

__global__ __launch_bounds__(128) void k_bscan() {
    __shared__ int s[128];
    int t = threadIdx.x;
    int v = g_bcnt[t];
    s[t] = v;
    __syncthreads();
    for (int off = 1; off < 128; off <<= 1) {
        int u = (t >= off) ? s[t - off] : 0;
        __syncthreads();
        s[t] += u;
        __syncthreads();
    }
    g_bbase[t] = s[t] - v;
    g_bcur[t] = s[t] - v;
    if (t == 127) g_bbase[128] = s[127];
}

__global__ __launch_bounds__(256) void k_bscatter(const int* __restrict__ src,
                                                  const int* __restrict__ dst) {
    __shared__ int h[128];
    __shared__ int base[128];
    if (threadIdx.x < 128) h[threadIdx.x] = 0;
    __syncthreads();
    int e0 = (blockIdx.x * 256 + threadIdx.x) * 4;
    int4 s = *(const int4*)&src[e0];
    int4 d = *(const int4*)&dst[e0];
    int b0 = d.x >> 9, b1 = d.y >> 9, b2 = d.z >> 9, b3 = d.w >> 9;
    atomicAdd(&h[b0], 1);
    atomicAdd(&h[b1], 1);
    atomicAdd(&h[b2], 1);
    atomicAdd(&h[b3], 1);
    __syncthreads();
    if (threadIdx.x < 128) {
        int c = h[threadIdx.x];
        base[threadIdx.x] = c ? atomicAdd(&g_bcur[threadIdx.x], c) : 0;
        h[threadIdx.x] = 0;
    }
    __syncthreads();
    int r0 = atomicAdd(&h[b0], 1);
    g_ebuck[base[b0] + r0] = ((unsigned int)(d.x & 511) << 16) | (unsigned int)s.x;
    int r1 = atomicAdd(&h[b1], 1);
    g_ebuck[base[b1] + r1] = ((unsigned int)(d.y & 511) << 16) | (unsigned int)s.y;
    int r2 = atomicAdd(&h[b2], 1);
    g_ebuck[base[b2] + r2] = ((unsigned int)(d.z & 511) << 16) | (unsigned int)s.z;
    int r3 = atomicAdd(&h[b3], 1);
    g_ebuck[base[b3] + r3] = ((unsigned int)(d.w & 511) << 16) | (unsigned int)s.w;
}

__global__ __launch_bounds__(512) void k_bcsr() {
    __shared__ int hist[512];
    __shared__ int offs[512];
    __shared__ int cur[512];
    int g = blockIdx.x, t = threadIdx.x;
    hist[t] = 0;
    cur[t] = 0;
    __syncthreads();
    int b0 = g_bbase[g], b1 = g_bbase[g + 1];
    for (int e = b0 + t; e < b1; e += 512) {
        unsigned int p = g_ebuck[e];
        atomicAdd(&hist[p >> 16], 1);
    }
    __syncthreads();
    int v = hist[t];
    offs[t] = v;
    __syncthreads();
    for (int off = 1; off < 512; off <<= 1) {
        int u = (t >= off) ? offs[t - off] : 0;
        __syncthreads();
        offs[t] += u;
        __syncthreads();
    }
    int excl = offs[t] - v;
    g_rows1[g * 512 + t] = b0 + excl;
    if (t == 511) g_rows1[g * 512 + 512] = b0 + excl + v;
    __syncthreads();
    offs[t] = excl;
    __syncthreads();
    for (int e = b0 + t; e < b1; e += 512) {
        unsigned int p = g_ebuck[e];
        int dl = p >> 16;
        int r = atomicAdd(&cur[dl], 1);
        g_csr1u[b0 + offs[dl] + r] = (unsigned short)(p & 0xFFFFu);
    }
}

// ---------------- fused conv: sliced gather + MFMA + epilogues --------------
// R8-R11 post-mortems distilled:
//  * fused gather of 256B rows = HBM-random-request-bound (84us, FETCH 162MB);
//  * split agg+mm with feature slices made gathers L2-hits (FETCH 19MB) but
//    re-paid ~160us in extra kernels/round-trips;
//  * global degree-perm scattered writes (WRITE 17->48MB): never permute the
//    store side.
// This kernel: gather loops feature-slices SEQUENTIALLY (slice working set 2MB
// -> L2-resident per XCD by temporal locality), 4 lanes/row so the 4 lane
// requests merge into ONE cache-line lookup per edge per slice, block-LOCAL
// degree sort equalizes wave iteration counts (thread->row remap only; LDS
// writes stay at the true row). Per-feature accumulation remains strictly
// e-ascending in a single thread -> numerics identical to the passing R10 path.
// Then: MFMA out = relu([agg | root] @ W + bias) with root read from the same
// slice buffer; epilogues: pool partials, DOTS score dots, slice-major emit.
template <int KA, int DEN, int MASKED, int DOTS, int OUTK>
__global__ __launch_bounds__(512, 4) void k_conv(int sbufId, int wsel, int wOfs,
                                                 const float* __restrict__ bias, int sec,
                                                 const float* __restrict__ pwr,
                                                 const float* __restrict__ pwt) {
    constexpr int F = (KA == 64) ? 8 : 16;   // feats per slice
    constexpr int FQ = F / 4;                // feats per lane (4 lanes/row)
    constexpr int STRA = KA + 8;             // gather-tile row stride (shorts)
    __shared__ unsigned short lds_a[128 * 136];   // gather tile / output tile
    __shared__ float s[128];
    __shared__ unsigned short sord[128];
    __shared__ int dh[64];
    __shared__ int db[64];
    const unsigned short* sb =
        (KA == 64) ? g_xbs : ((sbufId == 2) ? g_hgs : g_hs1);
    const unsigned short* Wt = (wsel ? g_wtc : g_wt1) + wOfs;
    int rowbase = blockIdx.x * 128;

    // ---- block-local degree sort (wave divergence killer, store-side safe) ----
    if (threadIdx.x < 64) dh[threadIdx.x] = 0;
    __syncthreads();
    if (threadIdx.x < 128) {
        int node = rowbase + threadIdx.x;
        int d = min(g_rows1[node + 1] - g_rows1[node], 63);
        atomicAdd(&dh[d], 1);
    }
    __syncthreads();
    if (threadIdx.x == 0) {
        int ss = 0;
        for (int i = 0; i < 64; i++) { db[i] = ss; ss += dh[i]; }
    }
    __syncthreads();
    if (threadIdx.x < 128) {
        int node = rowbase + threadIdx.x;
        int d = min(g_rows1[node + 1] - g_rows1[node], 63);
        int p = atomicAdd(&db[d], 1);
        sord[p] = (unsigned short)threadIdx.x;
    }
    __syncthreads();

    // ---- phase 1: slice-sequential gather-aggregate into LDS ----
    {
        int row = sord[threadIdx.x >> 2];
        int q = threadIdx.x & 3;
        int node = rowbase + row;
        int r0 = g_rows1[node], r1 = g_rows1[node + 1];
        float inv;
        if (DEN) {
            inv = g_kinv[node];
        } else {
            int c = r1 - r0;
            inv = 1.0f / (float)(c > 0 ? c : 1);
        }
#pragma unroll 1
        for (int sl = 0; sl < 8; sl++) {
            const unsigned short* sp = sb + ((size_t)sl * NT) * F + q * FQ;
            float acc[FQ];
#pragma unroll
            for (int i = 0; i < FQ; i++) acc[i] = 0.f;

#define BODY(ii) {                                                   \
    if constexpr (FQ == 4) {                                         \
        uint2 v = *(const uint2*)&sp[(size_t)(ii) * 16];             \
        acc2(acc, v.x); acc2(acc + 2, v.y);                          \
    } else {                                                         \
        unsigned int v = *(const unsigned int*)&sp[(size_t)(ii) * 8];\
        acc2(acc, v);                                                \
    }                                                                \
}
            int e = r0;
            for (; e < r1 && (e & 3); e++) BODY((int)g_csr1u[e]);
            for (; e + 4 <= r1; e += 4) {
                uint2 iv = *(const uint2*)&g_csr1u[e];
                BODY((int)(iv.x & 0xffffu));
                BODY((int)(iv.x >> 16));
                BODY((int)(iv.y & 0xffffu));
                BODY((int)(iv.y >> 16));
            }
            for (; e < r1; e++) BODY((int)g_csr1u[e]);
#undef BODY
            if constexpr (FQ == 4) {
                *(uint2*)&lds_a[row * STRA + sl * F + q * 4] =
                    make_uint2(pk2(acc[0] * inv, acc[1] * inv),
                               pk2(acc[2] * inv, acc[3] * inv));
            } else {
                *(unsigned int*)&lds_a[row * STRA + sl * F + q * 2] =
                    pk2(acc[0] * inv, acc[1] * inv);
            }
        }
    }
    if (threadIdx.x < 128) s[threadIdx.x] = 0.f;
    __syncthreads();

    // ---- phase 2: MFMA (8 waves x 16-row tiles) ----
    const int K = 2 * KA;
    int lane = threadIdx.x & 63;
    int w = threadIdx.x >> 6;              // 0..7
    int n16 = lane & 15, quad = lane >> 4;
    int rowloc = w * 16;
    int rowg = rowbase + rowloc;
    int g = blockIdx.x >> 2, qb = blockIdx.x & 3;
    f32x4 acc[8];
#pragma unroll
    for (int ct = 0; ct < 8; ct++)
#pragma unroll
        for (int i = 0; i < 4; i++) acc[ct][i] = 0.f;

#pragma unroll
    for (int ks = 0; ks < K / 32; ks++) {
        int k0 = ks * 32;
        bf16x8 a0;
        if (k0 < KA) {
            a0 = *(const bf16x8*)&lds_a[(rowloc + n16) * STRA + k0 + quad * 8];
        } else {
            int col = k0 - KA + quad * 8;
            if constexpr (KA == 64) {
                int fg = col >> 3;
                a0 = *(const bf16x8*)&sb[((size_t)fg * NT + rowg + n16) * 8];
            } else {
                int fg = col >> 4, off = col & 15;
                a0 = *(const bf16x8*)&sb[((size_t)fg * NT + rowg + n16) * 16 + off];
            }
        }
#pragma unroll
        for (int ct = 0; ct < 8; ct++) {
            bf16x8 b = *(const bf16x8*)&Wt[(size_t)(ct * 16 + n16) * K + k0 + quad * 8];
            acc[ct] = __builtin_amdgcn_mfma_f32_16x16x32_bf16(a0, b, acc[ct], 0, 0, 0);
        }
    }
    __syncthreads();   // lds_a reads done; safe to overwrite as output tile

    // bias + relu + mask; store (row-major global or LDS tile); keep in acc
    {
        float m[4];
#pragma unroll
        for (int i = 0; i < 4; i++) {
            int r = rowg + quad * 4 + i;
            m[i] = (!MASKED || g_keptu[r]) ? 1.0f : 0.0f;
        }
#pragma unroll
        for (int ct = 0; ct < 8; ct++) {
            int c = ct * 16 + n16;
            float bv = bias[c];
#pragma unroll
            for (int i = 0; i < 4; i++) {
                float v = fmaxf(acc[ct][i] + bv, 0.f) * m[i];
                acc[ct][i] = v;
                if constexpr (OUTK == 1)
                    g_hb2[(size_t)(rowg + quad * 4 + i) * 128 + c] = f2b(v);
                if constexpr (OUTK == 2)
                    lds_a[(rowloc + quad * 4 + i) * 136 + c] = f2b(v);
            }
        }
    }

    // pool epilogue: column sums over this block's 128 rows (each wave adds 16)
#pragma unroll
    for (int ct = 0; ct < 8; ct++) {
        float p = 0.f;
#pragma unroll
        for (int i = 0; i < 4; i++) p += acc[ct][i];
        p += __shfl_xor(p, 16);
        p += __shfl_xor(p, 32);
        if (quad == 0) atomicAdd(&s[ct * 16 + n16], p);
    }

    // DOTS epilogue (conv2): row dots with pwr/pwt
    if (DOTS) {
        float pr[8], pt[8];
#pragma unroll
        for (int ct = 0; ct < 8; ct++) {
            pr[ct] = pwr[ct * 16 + n16];
            pt[ct] = pwt[ct * 16 + n16];
        }
#pragma unroll
        for (int i = 0; i < 4; i++) {
            float dr = 0.f, dt = 0.f;
#pragma unroll
            for (int ct = 0; ct < 8; ct++) {
                dr += acc[ct][i] * pr[ct];
                dt += acc[ct][i] * pt[ct];
            }
            dr += __shfl_xor(dr, 1); dt += __shfl_xor(dt, 1);
            dr += __shfl_xor(dr, 2); dt += __shfl_xor(dt, 2);
            dr += __shfl_xor(dr, 4); dt += __shfl_xor(dt, 4);
            dr += __shfl_xor(dr, 8); dt += __shfl_xor(dt, 8);
            if (n16 == 0) {
                int r = rowg + quad * 4 + i;
                g_trel[r] = dr;
                g_troot[r] = dt;
            }
        }
    }
    __syncthreads();
    if (threadIdx.x < 128)
        g_xc4[((sec * NB + g) * 4 + qb) * 128 + threadIdx.x] = s[threadIdx.x];

    // slice-major emit (coalesced 16B stores; tile synced above)
    if constexpr (OUTK == 2) {
#pragma unroll
        for (int rep = 0; rep < 4; rep++) {
            int chunk = rep * 512 + threadIdx.x;   // 2048 x 16B
            int s_ = chunk >> 8, rem = chunk & 255;
            int nl = rem >> 1, hf = rem & 1;
            bf16x8 val = *(const bf16x8*)&lds_a[nl * 136 + s_ * 16 + hf * 8];
            *(bf16x8*)&g_hs1[((size_t)s_ * NT + rowbase + nl) * 16 + hf * 8] = val;
        }
    }
}

// ---------------- kinv precompute (kept-neighbor counts, post-topk) ---------
__global__ __launch_bounds__(256) void k_kinv() {
    int node = blockIdx.x * 256 + threadIdx.x;
    int r0 = g_rows1[node], r1 = g_rows1[node + 1];
    int kc = 0;
    int e = r0;
    for (; e < r1 && (e & 3); e++) kc += (int)g_keptu[g_csr1u[e]];
    for (; e + 4 <= r1; e += 4) {
        uint2 iv = *(const uint2*)&g_csr1u[e];
        kc += (int)g_keptu[iv.x & 0xffffu] + (int)g_keptu[iv.x >> 16]
            + (int)g_keptu[iv.y & 0xffffu] + (int)g_keptu[iv.y >> 16];
    }
    for (; e < r1; e++) kc += (int)g_keptu[g_csr1u[e]];
    g_kinv[node] = 1.0f / (float)(kc > 0 ? kc : 1);
}

// ---------------- gate premultiply: h2 row-major -> gated slice-major -------
__global__ __launch_bounds__(256) void k_gateS() {
    int tid = blockIdx.x * 256 + threadIdx.x;   // over NT*8
    int n = tid >> 3, s = tid & 7;
    float g = g_gatef[n];
    const unsigned short* srcp = &g_hb2[(size_t)n * 128 + s * 16];
    uint4 a = *(const uint4*)srcp;
    uint4 b = *(const uint4*)(srcp + 8);
    uint4 oa, ob;
    oa.x = mul2(a.x, g); oa.y = mul2(a.y, g); oa.z = mul2(a.z, g); oa.w = mul2(a.w, g);
    ob.x = mul2(b.x, g); ob.y = mul2(b.y, g); ob.z = mul2(b.z, g); ob.w = mul2(b.w, g);
    unsigned short* d = &g_hgs[((size_t)s * NT + n) * 16];
    *(uint4*)d = oa;
    *(uint4*)(d + 8) = ob;
}

// ---------------- SAGPool: fused score + per-graph bitonic top-410 ----------
__global__ __launch_bounds__(256) void k_topk(const float* __restrict__ pb) {
    __shared__ float sv[512];
    __shared__ int si[512];
    int g = blockIdx.x, t = threadIdx.x;
    float pbv = pb[0];
    for (int l = t; l < 512; l += 256) {
        int node = g * 512 + l;
        int r0 = g_rows1[node], r1 = g_rows1[node + 1];
        float s = 0.f;
        int e = r0;
        for (; e + 4 <= r1; e += 4) {
            float s0 = g_trel[g_csr1u[e]];
            float s1 = g_trel[g_csr1u[e + 1]];
            float s2 = g_trel[g_csr1u[e + 2]];
            float s3 = g_trel[g_csr1u[e + 3]];
            s += (s0 + s1) + (s2 + s3);
        }
        for (; e < r1; e++) s += g_trel[g_csr1u[e]];
        sv[l] = s + g_troot[node] + pbv;
        si[l] = l;
    }
    __syncthreads();
    for (int k = 2; k <= 512; k <<= 1) {
        for (int j = k >> 1; j > 0; j >>= 1) {
            for (int i = t; i < 512; i += 256) {
                int p = i ^ j;
                if (p > i) {
                    float va = sv[i], vb = sv[p];
                    int ia = si[i], ib = si[p];
                    bool aFirst = (va > vb) || (va == vb && ia < ib);
                    bool up = ((i & k) == 0);
                    if (up != aFirst) { sv[i] = vb; sv[p] = va; si[i] = ib; si[p] = ia; }
                }
            }
            __syncthreads();
        }
    }
    for (int r = t; r < 512; r += 256) {
        int old = g * 512 + si[r];
        if (r < KK) {
            g_gatef[old] = tanhf(sv[r]);
            g_keptu[old] = 1;
        } else {
            g_gatef[old] = 0.f;
            g_keptu[old] = 0;
        }
    }
}

// ---------------- MLP head + log_softmax ------------------------------------
__global__ __launch_bounds__(128) void k_head(const float* __restrict__ W1, const float* __restrict__ b1,
                                              const float* __restrict__ W2, const float* __restrict__ b2,
                                              float* __restrict__ out) {
    __shared__ float xr[512];
    __shared__ float r0[128], r1[128];
    int g = blockIdx.x, t = threadIdx.x;
    for (int i = t; i < 512; i += 128) {
        int sec = i >> 7, c = i & 127;
        const float* p = &g_xc4[((sec * NB + g) * 4) * 128 + c];
        float v = p[0] + p[128] + p[256] + p[384];
        float inv = (sec < 2) ? (1.0f / 512.0f) : (1.0f / 410.0f);
        xr[i] = v * inv;
    }
    __syncthreads();
    float acc = b1[t];
    for (int k = 0; k < 512; k++) acc += xr[k] * W1[k * 128 + t];
    acc = fmaxf(acc, 0.f);
    r0[t] = acc * W2[t * 2 + 0];
    r1[t] = acc * W2[t * 2 + 1];
    __syncthreads();
    for (int off = 64; off > 0; off >>= 1) {
        if (t < off) { r0[t] += r0[t + off]; r1[t] += r1[t + off]; }
        __syncthreads();
    }
    if (t == 0) {
        float z0 = r0[0] + b2[0], z1 = r1[0] + b2[1];
        float m = fmaxf(z0, z1);
        float l = m + logf(expf(z0 - m) + expf(z1 - m));
        out[g * 2 + 0] = z0 - l;
        out[g * 2 + 1] = z1 - l;
    }
}

// ---------------- launch -----------------------------------------------------
extern "C" void kernel_launch(void* const* d_in, const int* in_sizes, int n_in,
                              void* d_out, int out_size, void* d_ws, size_t ws_size,
                              hipStream_t stream) {
    const float* x = (const float*)d_in[0];
    const int* ei = (const int*)d_in[1];
    const int* src = ei;
    const int* dst = ei + EE;
    const float* W1r = (const float*)d_in[3];
    const float* W1o = (const float*)d_in[4];
    const float* b1 = (const float*)d_in[5];
    const float* Wcr = (const float*)d_in[6];
    const float* Wco = (const float*)d_in[7];
    const float* bc = (const float*)d_in[8];
    const float* pwr = (const float*)d_in[9];
    const float* pwt = (const float*)d_in[10];
    const float* pb = (const float*)d_in[11];
    const float* l1W = (const float*)d_in[12];
    const float* l1b = (const float*)d_in[13];
    const float* l2W = (const float*)d_in[14];
    const float* l2b = (const float*)d_in[15];
    float* out = (float*)d_out;

    // ---- prep (x->bf16 slice-major, weights->bf16, zero bcnt) ----
    k_prep<<<(1048576 + 16384 + 98304 + 128 + 255) / 256, 256, 0, stream>>>(x, W1r, W1o, Wcr, Wco);

    // ---- CSR1 via counting sort (fence-free: kernel boundaries do the sync) ----
    k_bhist<<<1024, 256, 0, stream>>>(dst);
    k_bscan<<<1, 128, 0, stream>>>();
    k_bscatter<<<1024, 256, 0, stream>>>(src, dst);
    k_bcsr<<<128, 512, 0, stream>>>();

    // ---- conv1: fused agg(x slices)+mm -> h1 slices (g_hs1); sec0 ----
    k_conv<64, 0, 0, 0, 2><<<512, 512, 0, stream>>>(0, 0, 0, b1, 0, pwr, pwt);

    // ---- conv2: fused agg(h1 slices)+mm -> h2 row-major (g_hb2); DOTS; sec1 ----
    k_conv<128, 0, 0, 1, 1><<<512, 512, 0, stream>>>(1, 1, 0, bc, 1, pwr, pwt);

    // ---- SAGPool: score + top-410 -> gatef/keptu; kinv; gate premultiply ----
    k_topk<<<NB, 256, 0, stream>>>(pb);
    k_kinv<<<NT / 256, 256, 0, stream>>>();
    k_gateS<<<2048, 256, 0, stream>>>();

    // ---- conv3: fused agg(gated h2 slices, kinv)+mm (root pre-gated, MASKED)
    //      -> h3 slices (g_hs1); sec2 ----
    k_conv<128, 1, 1, 0, 2><<<512, 512, 0, stream>>>(2, 1, 32768, bc + 128, 2, pwr, pwt);

    // ---- conv4: fused agg(h3 slices, kinv)+mm (MASKED, pool-only); sec3 ----
    k_conv<128, 1, 1, 0, 0><<<512, 512, 0, stream>>>(1, 1, 65536, bc + 256, 3, pwr, pwt);

    // ---- head ----
    k_head<<<NB, 128, 0, stream>>>(l1W, l1b, l2W, l2b, out);
}

// Round 6
// 513.570 us; speedup vs baseline: 1.2266x; 1.2266x over previous
//
#include <hip/hip_runtime.h>
#include <math.h>

#define NT 65536
#define EE 1048576
#define NB 128
#define KK 410          // kept nodes per graph = ceil(0.8*512)
#define HH 128

typedef short bf16x8 __attribute__((ext_vector_type(8)));
typedef float f32x4 __attribute__((ext_vector_type(4)));
typedef unsigned int u32x4 __attribute__((ext_vector_type(4)));

// ---------------- device scratch -------------------------------------------
// Slice-major layouts ([slice][node][F]) + slice = blockIdx&7: round-robin
// block->XCD dispatch concentrates slice s on XCD s -> gathers are L2-hits
// (R10 MEASURED: FETCH 162->19MB). R12 disproved the temporal-phasing variant
// (fused slice loop: FETCH 129MB) -- the kernel-wide fixed slice is the
// mechanism that works. Never permute global store order (R11: WRITE 17->48MB).
__device__ __align__(16) unsigned short g_xbs[(size_t)8 * NT * 8];   // x bf16 [8][NT][8]
__device__ __align__(16) unsigned short g_hs1[(size_t)8 * NT * 16];  // h1 (then h3) bf16 [8][NT][16]
__device__ __align__(16) unsigned short g_hgs[(size_t)8 * NT * 16];  // gated h2 bf16 [8][NT][16]
__device__ __align__(16) unsigned short g_hb2[(size_t)NT * HH];      // h2 row-major (gateS input)
__device__ __align__(16) unsigned char  g_h8b[(size_t)8 * NT * 16];  // h3 e4m4 [8][NT][16] (conv4 gather)
__device__ __align__(16) unsigned short g_agg[(size_t)16 * NT * 8];  // agg bf16 [group8][node][8]
__device__ __align__(16) unsigned short g_wt1[128 * 128];
__device__ __align__(16) unsigned short g_wtc[3 * 128 * 256];
__device__ __align__(16) unsigned short g_csr1u[EE];   // src id per edge, grouped by dst
__device__ unsigned short g_keptu[NT];   // 1 if node kept by SAGPool
__device__ unsigned int g_ebuck[EE];     // packed (dstLocal<<16)|src, bucketed by graph
__device__ int g_bcnt[128];
__device__ int g_bbase[129];
__device__ int g_bcur[128];
__device__ float g_trel[NT];
__device__ float g_troot[NT];
__device__ float g_gatef[NT];            // tanh(score) if kept else 0
__device__ float g_kinv[NT];             // 1/max(kept-neighbor count,1)
__device__ float g_xc4[4 * NB * 4 * 128]; // pooled partials [sec][graph][quarter][128]
__device__ int g_rows1[NT + 1];

__device__ __forceinline__ float b2f(unsigned short u) {
    union { unsigned int i; float f; } v;
    v.i = ((unsigned int)u) << 16;
    return v.f;
}
__device__ __forceinline__ unsigned short f2b(float f) {
    unsigned int x = __float_as_uint(f);
    unsigned int r = x + 0x7fffu + ((x >> 16) & 1u);   // round-to-nearest-even
    return (unsigned short)(r >> 16);
}
__device__ __forceinline__ unsigned int pk2(float a, float b) {
    return (unsigned int)f2b(a) | ((unsigned int)f2b(b) << 16);
}
__device__ __forceinline__ unsigned int mul2(unsigned int wd, float g) {
    float lo = b2f((unsigned short)(wd & 0xffffu)) * g;
    float hi = b2f((unsigned short)(wd >> 16)) * g;
    return pk2(lo, hi);
}
// ---- custom unsigned e4m4 (post-relu values >= 0): v = (1+m/16)*2^(e-7) ----
__device__ __forceinline__ unsigned char enc8(float v) {
    v = fminf(v, 496.0f);
    unsigned int b = __float_as_uint(v * 0x1p-120f);
    unsigned int r = (b + 0x3ffffu + ((b >> 19) & 1u)) >> 19;
    return (unsigned char)r;
}
#define DEC8(u) ((u) ? __uint_as_float(((unsigned int)(u) << 19) + 0x3C000000u) : 0.0f)

// ---------------- prep: x->bf16 slice-major, weights, zero bcnt -------------
// NOTE (R7): no grid-wide fences on CDNA4 (per-XCD L2) — kernel boundaries sync.
__global__ void k_prep(const float* __restrict__ x,
                       const float* __restrict__ W1r, const float* __restrict__ W1o,
                       const float* __restrict__ Wcr, const float* __restrict__ Wco) {
    int tid = blockIdx.x * 256 + threadIdx.x;
    if (tid < 1048576) {
        float4 v = *(const float4*)&x[(size_t)tid * 4];
        unsigned int lo = pk2(v.x, v.y);
        unsigned int hi = pk2(v.z, v.w);
        int node = tid >> 4;
        int sl = (tid & 15) >> 1;
        int of = (tid & 1) * 4;
        *(uint2*)&g_xbs[(((size_t)sl) * NT + node) * 8 + of] = make_uint2(lo, hi);
    } else if (tid < 1048576 + 16384) {
        int r = tid - 1048576;
        int k = r & 127, n = r >> 7;
        float v = (k < 64) ? W1r[k * 128 + n] : W1o[(k - 64) * 128 + n];
        g_wt1[n * 128 + k] = f2b(v);
    } else if (tid < 1048576 + 16384 + 98304) {
        int r = tid - (1048576 + 16384);
        int l = r >> 15;
        int k = r & 255, n = (r >> 8) & 127;
        float v = (k < 128) ? Wcr[l * 16384 + k * 128 + n]
                            : Wco[l * 16384 + (k - 128) * 128 + n];
        g_wtc[l * 32768 + n * 256 + k] = f2b(v);
    } else if (tid < 1048576 + 16384 + 98304 + 128) {
        g_bcnt[tid - (1048576 + 16384 + 98304)] = 0;
    }
}

// ---------------- CSR1 build: 2-level counting sort -------------------------
__global__ __launch_bounds__(256) void k_bhist(const int* __restrict__ dst) {
    __shared__ int h[128];
    if (threadIdx.x < 128) h[threadIdx.x] = 0;
    __syncthreads();
    int e0 = (blockIdx.x * 256 + threadIdx.x) * 4;
    int4 d = *(const int4*)&dst[e0];
    atomicAdd(&h[d.x >> 9], 1);
    atomicAdd(&h[d.y >> 9], 1);
    atomicAdd(&h[d.z >> 9], 1);
    atomicAdd(&h[d.w >> 9], 1);
    __syncthreads();
    if (threadIdx.x < 128 && h[threadIdx.x]) atomicAdd(&g_bcnt[threadIdx.x], h[threadIdx.x]);
}

__global__ __launch_bounds__(128) void k_bscan() {
    __shared__ int s[128];
    int t = threadIdx.x;
    int v = g_bcnt[t];
    s[t] = v;
    __syncthreads();
    for (int off = 1; off < 128; off <<= 1) {
        int u = (t >= off) ? s[t - off] : 0;
        __syncthreads();
        s[t] += u;
        __syncthreads();
    }
    g_bbase[t] = s[t] - v;
    g_bcur[t] = s[t] - v;
    if (t == 127) g_bbase[128] = s[127];
}

__global__ __launch_bounds__(256) void k_bscatter(const int* __restrict__ src,
                                                  const int* __restrict__ dst) {
    __shared__ int h[128];
    __shared__ int base[128];
    if (threadIdx.x < 128) h[threadIdx.x] = 0;
    __syncthreads();
    int e0 = (blockIdx.x * 256 + threadIdx.x) * 4;
    int4 s = *(const int4*)&src[e0];
    int4 d = *(const int4*)&dst[e0];
    int b0 = d.x >> 9, b1 = d.y >> 9, b2 = d.z >> 9, b3 = d.w >> 9;
    atomicAdd(&h[b0], 1);
    atomicAdd(&h[b1], 1);
    atomicAdd(&h[b2], 1);
    atomicAdd(&h[b3], 1);
    __syncthreads();
    if (threadIdx.x < 128) {
        int c = h[threadIdx.x];
        base[threadIdx.x] = c ? atomicAdd(&g_bcur[threadIdx.x], c) : 0;
        h[threadIdx.x] = 0;
    }
    __syncthreads();
    int r0 = atomicAdd(&h[b0], 1);
    g_ebuck[base[b0] + r0] = ((unsigned int)(d.x & 511) << 16) | (unsigned int)s.x;
    int r1 = atomicAdd(&h[b1], 1);
    g_ebuck[base[b1] + r1] = ((unsigned int)(d.y & 511) << 16) | (unsigned int)s.y;
    int r2 = atomicAdd(&h[b2], 1);
    g_ebuck[base[b2] + r2] = ((unsigned int)(d.z & 511) << 16) | (unsigned int)s.z;
    int r3 = atomicAdd(&h[b3], 1);
    g_ebuck[base[b3] + r3] = ((unsigned int)(d.w & 511) << 16) | (unsigned int)s.w;
}

__global__ __launch_bounds__(512) void k_bcsr() {
    __shared__ int hist[512];
    __shared__ int offs[512];
    __shared__ int cur[512];
    int g = blockIdx.x, t = threadIdx.x;
    hist[t] = 0;
    cur[t] = 0;
    __syncthreads();
    int b0 = g_bbase[g], b1 = g_bbase[g + 1];
    for (int e = b0 + t; e < b1; e += 512) {
        unsigned int p = g_ebuck[e];
        atomicAdd(&hist[p >> 16], 1);
    }
    __syncthreads();
    int v = hist[t];
    offs[t] = v;
    __syncthreads();
    for (int off = 1; off < 512; off <<= 1) {
        int u = (t >= off) ? offs[t - off] : 0;
        __syncthreads();
        offs[t] += u;
        __syncthreads();
    }
    int excl = offs[t] - v;
    g_rows1[g * 512 + t] = b0 + excl;
    if (t == 511) g_rows1[g * 512 + 512] = b0 + excl + v;
    __syncthreads();
    offs[t] = excl;
    __syncthreads();
    for (int e = b0 + t; e < b1; e += 512) {
        unsigned int p = g_ebuck[e];
        int dl = p >> 16;
        int r = atomicAdd(&cur[dl], 1);
        g_csr1u[b0 + offs[dl] + r] = (unsigned short)(p & 0xFFFFu);
    }
}

// ---------------- sliced gather-aggregate -----------------------------------
// Measured facts folded in:
//  * slice = blockIdx&7 -> XCD-resident gather (R10: FETCH 19MB) -- keep;
//  * cost tracks lane-address count (R10: 18M addr ~ 51us incl. divergence);
//  * wave divergence ~1.7x (Poisson-16 max-of-64); fix with BLOCK-LOCAL degree
//    sort: permutes thread->node only; the block's whole output window is still
//    written by this block -> full-line writebacks (R11's global perm scattered
//    them: WRITE 17->48MB);
//  * LPR=2 (2 lanes/row, 16B each): halves per-lane loads; pair addresses share
//    a 64B line (merge candidate); writes perfectly coalesced;
//  * conv4 gathers e4m4 (R9-proven: absmax unchanged): 1 addr/edge/slice.
// Accumulation per feature stays strictly e-ascending in one lane ->
// conv1/conv2 sums bit-identical -> top-k selection preserved.
template <int F, int DEN, int FP8, int LPR>
__global__ __launch_bounds__(256) void k_agg(int srcId) {
    constexpr int NPB = 256 / LPR;          // nodes per block
    __shared__ int dh[64];
    __shared__ int db[64];
    __shared__ unsigned short sord[NPB];
    int s = blockIdx.x & 7;
    int nodebase = (blockIdx.x >> 3) * NPB;
    int t = threadIdx.x;

    // ---- block-local degree sort ----
    if (t < 64) dh[t] = 0;
    __syncthreads();
    int dcap = 0;
    if (t < NPB) {
        int n = nodebase + t;
        dcap = min(g_rows1[n + 1] - g_rows1[n], 63);
        atomicAdd(&dh[dcap], 1);
    }
    __syncthreads();
    if (t == 0) {
        int ss = 0;
#pragma unroll
        for (int i = 0; i < 64; i++) { db[i] = ss; ss += dh[i]; }
    }
    __syncthreads();
    if (t < NPB) {
        int p = atomicAdd(&db[dcap], 1);
        sord[p] = (unsigned short)t;
    }
    __syncthreads();

    int row = sord[t / LPR];
    int half = (LPR == 2) ? (t & 1) : 0;
    int node = nodebase + row;

    const unsigned short* sp = nullptr;
    const unsigned char* sp8 = nullptr;
    if constexpr (FP8) {
        sp8 = g_h8b + (size_t)s * NT * 16;
    } else if constexpr (F == 8) {
        sp = g_xbs + (size_t)s * NT * 8;
    } else {
        sp = (srcId == 0 ? g_hs1 : g_hgs) + (size_t)s * NT * 16 + half * 8;
    }
    int r0 = g_rows1[node], r1 = g_rows1[node + 1];
    float inv;
    if (DEN) {
        inv = g_kinv[node];
    } else {
        int c = r1 - r0;
        inv = 1.0f / (float)(c > 0 ? c : 1);
    }
    constexpr int NA = FP8 ? 16 : 8;
    float acc[NA];
#pragma unroll
    for (int i = 0; i < NA; i++) acc[i] = 0.f;

#define ACCP(wd, J) { acc[J] += b2f((unsigned short)((wd) & 0xffffu)); acc[(J) + 1] += b2f((unsigned short)((wd) >> 16)); }
    auto body = [&](int ii) {
        if constexpr (FP8) {
            uint4 w = *(const uint4*)&sp8[(size_t)ii * 16];
            acc[0] += DEC8(w.x & 0xffu);
            acc[1] += DEC8((w.x >> 8) & 0xffu);
            acc[2] += DEC8((w.x >> 16) & 0xffu);
            acc[3] += DEC8(w.x >> 24);
            acc[4] += DEC8(w.y & 0xffu);
            acc[5] += DEC8((w.y >> 8) & 0xffu);
            acc[6] += DEC8((w.y >> 16) & 0xffu);
            acc[7] += DEC8(w.y >> 24);
            acc[8] += DEC8(w.z & 0xffu);
            acc[9] += DEC8((w.z >> 8) & 0xffu);
            acc[10] += DEC8((w.z >> 16) & 0xffu);
            acc[11] += DEC8(w.z >> 24);
            acc[12] += DEC8(w.w & 0xffu);
            acc[13] += DEC8((w.w >> 8) & 0xffu);
            acc[14] += DEC8((w.w >> 16) & 0xffu);
            acc[15] += DEC8(w.w >> 24);
        } else if constexpr (F == 8) {
            uint4 v = *(const uint4*)&sp[(size_t)ii * 8];
            ACCP(v.x, 0) ACCP(v.y, 2) ACCP(v.z, 4) ACCP(v.w, 6)
        } else {
            uint4 v = *(const uint4*)&sp[(size_t)ii * 16];
            ACCP(v.x, 0) ACCP(v.y, 2) ACCP(v.z, 4) ACCP(v.w, 6)
        }
    };
#undef ACCP

    int e = r0;
    for (; e < r1 && (e & 3); e++) body((int)g_csr1u[e]);
    for (; e + 4 <= r1; e += 4) {
        uint2 iv = *(const uint2*)&g_csr1u[e];
        body((int)(iv.x & 0xffffu));
        body((int)(iv.x >> 16));
        body((int)(iv.y & 0xffffu));
        body((int)(iv.y >> 16));
    }
    for (; e < r1; e++) body((int)g_csr1u[e]);

    // group index: F=8 -> s; F=16 bf16 -> 2s+half; FP8 -> 2s and 2s+1
    int gb0 = (F == 8) ? s : (2 * s + half);
    u32x4 o;
    o[0] = pk2(acc[0] * inv, acc[1] * inv);
    o[1] = pk2(acc[2] * inv, acc[3] * inv);
    o[2] = pk2(acc[4] * inv, acc[5] * inv);
    o[3] = pk2(acc[6] * inv, acc[7] * inv);
    __builtin_nontemporal_store(o, (u32x4*)&g_agg[((size_t)gb0 * NT + node) * 8]);
    if constexpr (FP8) {
        u32x4 o2;
        o2[0] = pk2(acc[8] * inv, acc[9] * inv);
        o2[1] = pk2(acc[10] * inv, acc[11] * inv);
        o2[2] = pk2(acc[12] * inv, acc[13] * inv);
        o2[3] = pk2(acc[14] * inv, acc[15] * inv);
        __builtin_nontemporal_store(o2, (u32x4*)&g_agg[((size_t)(2 * s + 1) * NT + node) * 8]);
    }
}

// ---------------- kinv precompute (kept-neighbor counts, post-topk) ---------
__global__ __launch_bounds__(256) void k_kinv() {
    int node = blockIdx.x * 256 + threadIdx.x;
    int r0 = g_rows1[node], r1 = g_rows1[node + 1];
    int kc = 0;
    int e = r0;
    for (; e < r1 && (e & 3); e++) kc += (int)g_keptu[g_csr1u[e]];
    for (; e + 4 <= r1; e += 4) {
        uint2 iv = *(const uint2*)&g_csr1u[e];
        kc += (int)g_keptu[iv.x & 0xffffu] + (int)g_keptu[iv.x >> 16]
            + (int)g_keptu[iv.y & 0xffffu] + (int)g_keptu[iv.y >> 16];
    }
    for (; e < r1; e++) kc += (int)g_keptu[g_csr1u[e]];
    g_kinv[node] = 1.0f / (float)(kc > 0 ? kc : 1);
}

// ---------------- gate premultiply: h2 row-major -> gated slice-major -------
__global__ __launch_bounds__(256) void k_gateS() {
    int tid = blockIdx.x * 256 + threadIdx.x;   // over NT*8
    int n = tid >> 3, s = tid & 7;
    float g = g_gatef[n];
    const unsigned short* srcp = &g_hb2[(size_t)n * 128 + s * 16];
    uint4 a = *(const uint4*)srcp;
    uint4 b = *(const uint4*)(srcp + 8);
    uint4 oa, ob;
    oa.x = mul2(a.x, g); oa.y = mul2(a.y, g); oa.z = mul2(a.z, g); oa.w = mul2(a.w, g);
    ob.x = mul2(b.x, g); ob.y = mul2(b.y, g); ob.z = mul2(b.z, g); ob.w = mul2(b.w, g);
    unsigned short* d = &g_hgs[((size_t)s * NT + n) * 16];
    *(uint4*)d = oa;
    *(uint4*)(d + 8) = ob;
}

// ---------------- MFMA conv: out = relu([agg | root] @ W + bias) ------------
// A-half from g_agg; root from slice-major buffers (ROOTK 0: g_xbs F=8,
// ROOTK 1: slice16 sel g_hs1/g_hgs). Outputs (OUTK): 0 none; 1 row-major g_hb2;
// 2 slice-major bf16 -> g_hs1 via LDS transpose (coalesced 16B stores);
// 3 = 2 + e4m4 slice-major -> g_h8b. Epilogues: pool partials; DOTS.
template <int KA, int KB, int MASKED, int DOTS, int ROOTK, int OUTK>
__global__ __launch_bounds__(256) void k_mm(int wsel, int wOfs,
                                            int rootSel,
                                            const float* __restrict__ bias, int sec,
                                            const float* __restrict__ pwr,
                                            const float* __restrict__ pwt) {
    __shared__ float s[128];
    __shared__ unsigned short t16[(OUTK >= 2) ? 128 * 136 : 2];
    const unsigned short* Wt = (wsel ? g_wtc : g_wt1) + wOfs;
    const unsigned short* sb = (ROOTK == 1) ? (rootSel ? g_hgs : g_hs1) : g_xbs;
    int rowbase = blockIdx.x * 128;
    const int K = KA + KB;
    int lane = threadIdx.x & 63;
    int w = threadIdx.x >> 6;
    int n16 = lane & 15, quad = lane >> 4;
    int rowloc = w * 32;
    int rowg = rowbase + rowloc;
    int g = blockIdx.x >> 2, qb = blockIdx.x & 3;
    f32x4 acc[2][8];
#pragma unroll
    for (int rt = 0; rt < 2; rt++)
#pragma unroll
        for (int ct = 0; ct < 8; ct++)
#pragma unroll
            for (int i = 0; i < 4; i++) acc[rt][ct][i] = 0.f;

#pragma unroll
    for (int ks = 0; ks < K / 32; ks++) {
        int k0 = ks * 32;
        bf16x8 a0, a1;
        if (k0 < KA) {
            int fg = (k0 + quad * 8) >> 3;
            a0 = *(const bf16x8*)&g_agg[((size_t)fg * NT + rowg + n16) * 8];
            a1 = *(const bf16x8*)&g_agg[((size_t)fg * NT + rowg + 16 + n16) * 8];
        } else {
            int col = k0 - KA + quad * 8;
            if constexpr (ROOTK == 0) {
                int fg = col >> 3;
                a0 = *(const bf16x8*)&g_xbs[((size_t)fg * NT + rowg + n16) * 8];
                a1 = *(const bf16x8*)&g_xbs[((size_t)fg * NT + rowg + 16 + n16) * 8];
            } else {
                int fg = col >> 4, off = col & 15;
                a0 = *(const bf16x8*)&sb[((size_t)fg * NT + rowg + n16) * 16 + off];
                a1 = *(const bf16x8*)&sb[((size_t)fg * NT + rowg + 16 + n16) * 16 + off];
            }
        }
#pragma unroll
        for (int ct = 0; ct < 8; ct++) {
            bf16x8 b = *(const bf16x8*)&Wt[(size_t)(ct * 16 + n16) * K + k0 + quad * 8];
            acc[0][ct] = __builtin_amdgcn_mfma_f32_16x16x32_bf16(a0, b, acc[0][ct], 0, 0, 0);
            acc[1][ct] = __builtin_amdgcn_mfma_f32_16x16x32_bf16(a1, b, acc[1][ct], 0, 0, 0);
        }
    }

    // bias + relu + mask; store (row-major or LDS tile); keep values in acc
    if (threadIdx.x < 128) s[threadIdx.x] = 0.f;
#pragma unroll
    for (int rt = 0; rt < 2; rt++) {
        float m[4];
#pragma unroll
        for (int i = 0; i < 4; i++) {
            int r = rowg + rt * 16 + quad * 4 + i;
            m[i] = (!MASKED || g_keptu[r]) ? 1.0f : 0.0f;
        }
#pragma unroll
        for (int ct = 0; ct < 8; ct++) {
            int c = ct * 16 + n16;
            float bv = bias[c];
#pragma unroll
            for (int i = 0; i < 4; i++) {
                int r = rowg + rt * 16 + quad * 4 + i;
                float v = fmaxf(acc[rt][ct][i] + bv, 0.f) * m[i];
                acc[rt][ct][i] = v;
                if constexpr (OUTK == 1) g_hb2[(size_t)r * 128 + c] = f2b(v);
                if constexpr (OUTK >= 2) t16[(rowloc + rt * 16 + quad * 4 + i) * 136 + c] = f2b(v);
            }
        }
    }
    __syncthreads();

    // pool epilogue: column sums over this block's 128 rows
#pragma unroll
    for (int ct = 0; ct < 8; ct++) {
        float p = 0.f;
#pragma unroll
        for (int rt = 0; rt < 2; rt++)
#pragma unroll
            for (int i = 0; i < 4; i++) p += acc[rt][ct][i];
        p += __shfl_xor(p, 16);
        p += __shfl_xor(p, 32);
        if (quad == 0) atomicAdd(&s[ct * 16 + n16], p);
    }

    // DOTS epilogue (conv2): row dots with pwr/pwt
    if (DOTS) {
        float pr[8], pt[8];
#pragma unroll
        for (int ct = 0; ct < 8; ct++) {
            pr[ct] = pwr[ct * 16 + n16];
            pt[ct] = pwt[ct * 16 + n16];
        }
#pragma unroll
        for (int rt = 0; rt < 2; rt++)
#pragma unroll
            for (int i = 0; i < 4; i++) {
                float dr = 0.f, dt = 0.f;
#pragma unroll
                for (int ct = 0; ct < 8; ct++) {
                    dr += acc[rt][ct][i] * pr[ct];
                    dt += acc[rt][ct][i] * pt[ct];
                }
                dr += __shfl_xor(dr, 1); dt += __shfl_xor(dt, 1);
                dr += __shfl_xor(dr, 2); dt += __shfl_xor(dt, 2);
                dr += __shfl_xor(dr, 4); dt += __shfl_xor(dt, 4);
                dr += __shfl_xor(dr, 8); dt += __shfl_xor(dt, 8);
                if (n16 == 0) {
                    int r = rowg + rt * 16 + quad * 4 + i;
                    g_trel[r] = dr;
                    g_troot[r] = dt;
                }
            }
    }
    __syncthreads();
    if (threadIdx.x < 128)
        g_xc4[((sec * NB + g) * 4 + qb) * 128 + threadIdx.x] = s[threadIdx.x];

    // slice-major emit (coalesced; tile synced above)
    if constexpr (OUTK >= 2) {
        int tid = threadIdx.x;
#pragma unroll
        for (int rep = 0; rep < 8; rep++) {
            int chunk = rep * 256 + tid;
            int s_ = chunk >> 8, rem = chunk & 255;
            int nl = rem >> 1, hf = rem & 1;
            bf16x8 val = *(const bf16x8*)&t16[nl * 136 + s_ * 16 + hf * 8];
            *(bf16x8*)&g_hs1[((size_t)s_ * NT + rowbase + nl) * 16 + hf * 8] = val;
        }
        if constexpr (OUTK == 3) {
#pragma unroll
            for (int rep = 0; rep < 4; rep++) {
                int chunk = rep * 256 + tid;
                int s_ = chunk >> 7, nl = chunk & 127;
                const unsigned short* p = &t16[nl * 136 + s_ * 16];
                unsigned int wq[4];
#pragma unroll
                for (int q = 0; q < 4; q++) {
                    unsigned int c0 = enc8(b2f(p[q * 4 + 0]));
                    unsigned int c1 = enc8(b2f(p[q * 4 + 1]));
                    unsigned int c2 = enc8(b2f(p[q * 4 + 2]));
                    unsigned int c3 = enc8(b2f(p[q * 4 + 3]));
                    wq[q] = c0 | (c1 << 8) | (c2 << 16) | (c3 << 24);
                }
                *(uint4*)&g_h8b[((size_t)s_ * NT + rowbase + nl) * 16] =
                    make_uint4(wq[0], wq[1], wq[2], wq[3]);
            }
        }
    }
}

// ---------------- SAGPool: fused score + per-graph bitonic top-410 ----------
__global__ __launch_bounds__(256) void k_topk(const float* __restrict__ pb) {
    __shared__ float sv[512];
    __shared__ int si[512];
    int g = blockIdx.x, t = threadIdx.x;
    float pbv = pb[0];
    for (int l = t; l < 512; l += 256) {
        int node = g * 512 + l;
        int r0 = g_rows1[node], r1 = g_rows1[node + 1];
        float s = 0.f;
        int e = r0;
        for (; e + 4 <= r1; e += 4) {
            float s0 = g_trel[g_csr1u[e]];
            float s1 = g_trel[g_csr1u[e + 1]];
            float s2 = g_trel[g_csr1u[e + 2]];
            float s3 = g_trel[g_csr1u[e + 3]];
            s += (s0 + s1) + (s2 + s3);
        }
        for (; e < r1; e++) s += g_trel[g_csr1u[e]];
        sv[l] = s + g_troot[node] + pbv;
        si[l] = l;
    }
    __syncthreads();
    for (int k = 2; k <= 512; k <<= 1) {
        for (int j = k >> 1; j > 0; j >>= 1) {
            for (int i = t; i < 512; i += 256) {
                int p = i ^ j;
                if (p > i) {
                    float va = sv[i], vb = sv[p];
                    int ia = si[i], ib = si[p];
                    bool aFirst = (va > vb) || (va == vb && ia < ib);
                    bool up = ((i & k) == 0);
                    if (up != aFirst) { sv[i] = vb; sv[p] = va; si[i] = ib; si[p] = ia; }
                }
            }
            __syncthreads();
        }
    }
    for (int r = t; r < 512; r += 256) {
        int old = g * 512 + si[r];
        if (r < KK) {
            g_gatef[old] = tanhf(sv[r]);
            g_keptu[old] = 1;
        } else {
            g_gatef[old] = 0.f;
            g_keptu[old] = 0;
        }
    }
}

// ---------------- MLP head + log_softmax ------------------------------------
__global__ __launch_bounds__(128) void k_head(const float* __restrict__ W1, const float* __restrict__ b1,
                                              const float* __restrict__ W2, const float* __restrict__ b2,
                                              float* __restrict__ out) {
    __shared__ float xr[512];
    __shared__ float r0[128], r1[128];
    int g = blockIdx.x, t = threadIdx.x;
    for (int i = t; i < 512; i += 128) {
        int sec = i >> 7, c = i & 127;
        const float* p = &g_xc4[((sec * NB + g) * 4) * 128 + c];
        float v = p[0] + p[128] + p[256] + p[384];
        float inv = (sec < 2) ? (1.0f / 512.0f) : (1.0f / 410.0f);
        xr[i] = v * inv;
    }
    __syncthreads();
    float acc = b1[t];
    for (int k = 0; k < 512; k++) acc += xr[k] * W1[k * 128 + t];
    acc = fmaxf(acc, 0.f);
    r0[t] = acc * W2[t * 2 + 0];
    r1[t] = acc * W2[t * 2 + 1];
    __syncthreads();
    for (int off = 64; off > 0; off >>= 1) {
        if (t < off) { r0[t] += r0[t + off]; r1[t] += r1[t + off]; }
        __syncthreads();
    }
    if (t == 0) {
        float z0 = r0[0] + b2[0], z1 = r1[0] + b2[1];
        float m = fmaxf(z0, z1);
        float l = m + logf(expf(z0 - m) + expf(z1 - m));
        out[g * 2 + 0] = z0 - l;
        out[g * 2 + 1] = z1 - l;
    }
}

// ---------------- launch -----------------------------------------------------
extern "C" void kernel_launch(void* const* d_in, const int* in_sizes, int n_in,
                              void* d_out, int out_size, void* d_ws, size_t ws_size,
                              hipStream_t stream) {
    const float* x = (const float*)d_in[0];
    const int* ei = (const int*)d_in[1];
    const int* src = ei;
    const int* dst = ei + EE;
    const float* W1r = (const float*)d_in[3];
    const float* W1o = (const float*)d_in[4];
    const float* b1 = (const float*)d_in[5];
    const float* Wcr = (const float*)d_in[6];
    const float* Wco = (const float*)d_in[7];
    const float* bc = (const float*)d_in[8];
    const float* pwr = (const float*)d_in[9];
    const float* pwt = (const float*)d_in[10];
    const float* pb = (const float*)d_in[11];
    const float* l1W = (const float*)d_in[12];
    const float* l1b = (const float*)d_in[13];
    const float* l2W = (const float*)d_in[14];
    const float* l2b = (const float*)d_in[15];
    float* out = (float*)d_out;

    // ---- prep (x->bf16 slice-major, weights->bf16, zero bcnt) ----
    k_prep<<<(1048576 + 16384 + 98304 + 128 + 255) / 256, 256, 0, stream>>>(x, W1r, W1o, Wcr, Wco);

    // ---- CSR1 via counting sort (fence-free: kernel boundaries do the sync) ----
    k_bhist<<<1024, 256, 0, stream>>>(dst);
    k_bscan<<<1, 128, 0, stream>>>();
    k_bscatter<<<1024, 256, 0, stream>>>(src, dst);
    k_bcsr<<<128, 512, 0, stream>>>();

    // ---- conv1: agg(xbs, F=8) -> mm([agg|x]@wt1) -> h1 slices (g_hs1); sec0 ----
    k_agg<8, 0, 0, 1><<<2048, 256, 0, stream>>>(0);
    k_mm<64, 64, 0, 0, 0, 2><<<512, 256, 0, stream>>>(0, 0, 0, b1, 0, pwr, pwt);

    // ---- conv2: agg(h1 slices, LPR=2) -> mm -> h2 row (g_hb2); DOTS; sec1 ----
    k_agg<16, 0, 0, 2><<<4096, 256, 0, stream>>>(0);
    k_mm<128, 128, 0, 1, 1, 1><<<512, 256, 0, stream>>>(1, 0, 0, bc, 1, pwr, pwt);

    // ---- SAGPool: score + top-410 -> gatef/keptu; kinv; gate premultiply ----
    k_topk<<<NB, 256, 0, stream>>>(pb);
    k_kinv<<<NT / 256, 256, 0, stream>>>();
    k_gateS<<<2048, 256, 0, stream>>>();

    // ---- conv3: agg(gated slices, kinv, LPR=2) -> mm (root=gated, MASKED)
    //      -> h3 slices (g_hs1) + e4m4 (g_h8b); sec2 ----
    k_agg<16, 1, 0, 2><<<4096, 256, 0, stream>>>(1);
    k_mm<128, 128, 1, 0, 1, 3><<<512, 256, 0, stream>>>(1, 32768, 1, bc + 128, 2, pwr, pwt);

    // ---- conv4: agg(e4m4 h3, kinv) -> mm (root=h3 slices, MASKED, pool-only); sec3 ----
    k_agg<16, 1, 1, 1><<<2048, 256, 0, stream>>>(0);
    k_mm<128, 128, 1, 0, 1, 0><<<512, 256, 0, stream>>>(1, 65536, 0, bc + 256, 3, pwr, pwt);

    // ---- head ----
    k_head<<<NB, 128, 0, stream>>>(l1W, l1b, l2W, l2b, out);
}